// Round 3
// baseline (780.122 us; speedup 1.0000x reference)
//
#include <hip/hip_runtime.h>
#include <stdint.h>
#include <math.h>

#define N_B 4
#define T_S 4096
#define D_M 1024
#define H_M 1536
#define NT  (N_B * T_S)   // 16384
#define G2  (2 * H_M)     // 3072
#define LCH 64            // timesteps per chunk
#define NCH 64            // chunks (LCH*NCH == T_S)

typedef __attribute__((ext_vector_type(8))) short short8;
typedef __attribute__((ext_vector_type(4))) float floatx4;

__device__ __forceinline__ unsigned short f2bf(float f) {
  unsigned u = __float_as_uint(f);
  u += 0x7fff + ((u >> 16) & 1);            // RNE
  return (unsigned short)(u >> 16);
}
__device__ __forceinline__ float bf2f(unsigned short u) {
  return __uint_as_float(((unsigned)u) << 16);
}
__device__ __forceinline__ float sigmoidf_(float x) { return 1.f / (1.f + __expf(-x)); }
__device__ __forceinline__ float softplusf_(float x) {
  return (x > 20.f) ? x : log1pf(__expf(x));
}
__device__ __forceinline__ float geluf_(float x) {
  return 0.5f * x * (1.f + erff(x * 0.70710678118654752f));
}

// ---------------- zero-fill fallback (diagnostic if ws_size too small) ----------------
__global__ void zero_out(float* __restrict__ out, int n) {
  int i = blockIdx.x * 256 + threadIdx.x;
  if (i < n) out[i] = 0.f;
}

// ---------------- f32 -> bf16 conversion (vectorized x4) ----------------
__global__ void cvt_bf16(const float* __restrict__ in, unsigned short* __restrict__ out, int n4) {
  int i = blockIdx.x * 256 + threadIdx.x;
  if (i >= n4) return;
  float4 v = ((const float4*)in)[i];
  ushort4 o;
  o.x = f2bf(v.x); o.y = f2bf(v.y); o.z = f2bf(v.z); o.w = f2bf(v.w);
  ((ushort4*)out)[i] = o;
}

// ---------------- bf16 MFMA GEMM: C[m,n] = sum_k A[m,k]*B[n,k] (+bias[n]) ----------------
// m97 structure: 128x128 tile, BK=32, 256 threads (4 waves, 2x2), 4x4 16x16x32 frags/wave,
// global_load_lds width 16. Output fp32 or bf16.
#define BM 128
#define BN 128
#define BK 32

template<bool BIAS, bool OUT_BF16>
__global__ void gemm_bt(const unsigned short* __restrict__ A,
                        const unsigned short* __restrict__ B,
                        void* __restrict__ Cv, const float* __restrict__ bias,
                        int N, int K) {
  __shared__ unsigned short As[BM * BK];
  __shared__ unsigned short Bs[BN * BK];
  const int tid  = threadIdx.x;
  const int lane = tid & 63;
  const int wave = tid >> 6;
  const int bm = blockIdx.y * BM;
  const int bn = blockIdx.x * BN;
  const int wm = (wave >> 1) * 64;
  const int wn = (wave & 1) * 64;

  floatx4 acc[4][4];
#pragma unroll
  for (int i = 0; i < 4; i++)
#pragma unroll
    for (int j = 0; j < 4; j++)
      acc[i][j] = (floatx4){0.f, 0.f, 0.f, 0.f};

  const int c0 = tid, c1 = tid + 256;
  const unsigned short* Ag0 = A + (size_t)(bm + (c0 >> 2)) * K + (c0 & 3) * 8;
  const unsigned short* Ag1 = A + (size_t)(bm + (c1 >> 2)) * K + (c1 & 3) * 8;
  const unsigned short* Bg0 = B + (size_t)(bn + (c0 >> 2)) * K + (c0 & 3) * 8;
  const unsigned short* Bg1 = B + (size_t)(bn + (c1 >> 2)) * K + (c1 & 3) * 8;
  unsigned short* As0 = As + c0 * 8;
  unsigned short* As1 = As + c1 * 8;
  unsigned short* Bs0 = Bs + c0 * 8;
  unsigned short* Bs1 = Bs + c1 * 8;

  const int fr = lane & 15;
  const int kg = (lane >> 4) * 8;

  for (int k0 = 0; k0 < K; k0 += BK) {
    __builtin_amdgcn_global_load_lds((__attribute__((address_space(1))) void*)(Ag0 + k0),
                                     (__attribute__((address_space(3))) void*)As0, 16, 0, 0);
    __builtin_amdgcn_global_load_lds((__attribute__((address_space(1))) void*)(Ag1 + k0),
                                     (__attribute__((address_space(3))) void*)As1, 16, 0, 0);
    __builtin_amdgcn_global_load_lds((__attribute__((address_space(1))) void*)(Bg0 + k0),
                                     (__attribute__((address_space(3))) void*)Bs0, 16, 0, 0);
    __builtin_amdgcn_global_load_lds((__attribute__((address_space(1))) void*)(Bg1 + k0),
                                     (__attribute__((address_space(3))) void*)Bs1, 16, 0, 0);
    __syncthreads();

    short8 af[4], bf[4];
#pragma unroll
    for (int i = 0; i < 4; i++) {
      af[i] = *(const short8*)(As + (wm + i * 16 + fr) * BK + kg);
      bf[i] = *(const short8*)(Bs + (wn + i * 16 + fr) * BK + kg);
    }
#pragma unroll
    for (int i = 0; i < 4; i++)
#pragma unroll
      for (int j = 0; j < 4; j++)
        acc[i][j] = __builtin_amdgcn_mfma_f32_16x16x32_bf16(af[i], bf[j], acc[i][j], 0, 0, 0);
    __syncthreads();
  }

  const int cn = lane & 15;
  const int rb = (lane >> 4) * 4;
#pragma unroll
  for (int j = 0; j < 4; j++) {
    const int col = bn + wn + j * 16 + cn;
    const float bv = BIAS ? bias[col] : 0.f;
#pragma unroll
    for (int i = 0; i < 4; i++) {
      const int row0 = bm + wm + i * 16 + rb;
#pragma unroll
      for (int r = 0; r < 4; r++) {
        float v = acc[i][j][r] + bv;
        size_t idx = (size_t)(row0 + r) * N + col;
        if (OUT_BF16) ((unsigned short*)Cv)[idx] = f2bf(v);
        else          ((float*)Cv)[idx] = v;
      }
    }
  }
}

// ---------------- depthwise causal conv (K=4) + bias ----------------
__global__ void conv_dw(const unsigned short* __restrict__ xbpre, const float* __restrict__ cw,
                        const float* __restrict__ cb, unsigned short* __restrict__ xbc16) {
  int h = blockIdx.x * 256 + threadIdx.x;
  int t = blockIdx.y;
  size_t nt = (size_t)blockIdx.z * T_S + t;
  const float w0 = cw[h * 4 + 0], w1 = cw[h * 4 + 1], w2 = cw[h * 4 + 2], w3 = cw[h * 4 + 3];
  size_t base = nt * H_M + h;
  float acc = cb[h] + w3 * bf2f(xbpre[base]);
  if (t >= 1) acc += w2 * bf2f(xbpre[base - H_M]);
  if (t >= 2) acc += w1 * bf2f(xbpre[base - 2 * (size_t)H_M]);
  if (t >= 3) acc += w0 * bf2f(xbpre[base - 3 * (size_t)H_M]);
  xbc16[base] = f2bf(acc);
}

// ---------------- chunked linear scan ----------------
__global__ void scan_A(const unsigned short* __restrict__ fg, const unsigned short* __restrict__ xbc,
                       const float* __restrict__ fb,
                       float* __restrict__ cA, float* __restrict__ cS) {
  int h = blockIdx.x * 256 + threadIdx.x;
  int ch = blockIdx.y;
  int n = blockIdx.z;
  const float c8 = 8.f * softplusf_(fb[h]);
  float ap = 1.f, s = 0.f;
  size_t r = (size_t)n * T_S + (size_t)ch * LCH;
  for (int i = 0; i < LCH; i++, r++) {
    float forget = bf2f(fg[r * G2 + h]);
    float inp    = bf2f(fg[r * G2 + H_M + h]);
    float xb     = bf2f(xbc[r * H_M + h]);
    float alpha = __expf(-c8 * sigmoidf_(forget));
    float beta  = sqrtf(1.f - alpha * alpha + 1e-6f);
    float xs    = beta * sigmoidf_(inp) * xb;
    s = alpha * s + xs;
    ap *= alpha;
  }
  size_t o = ((size_t)n * NCH + ch) * H_M + h;
  cA[o] = ap;
  cS[o] = s;
}

__global__ void scan_B(const float* __restrict__ cA, const float* __restrict__ cS,
                       float* __restrict__ carry) {
  int h = blockIdx.x * 256 + threadIdx.x;
  int n = blockIdx.y;
  float cur = 0.f;
  for (int ch = 0; ch < NCH; ch++) {
    size_t o = ((size_t)n * NCH + ch) * H_M + h;
    carry[o] = cur;
    cur = cA[o] * cur + cS[o];
  }
}

// phase C: replay with carry-in; gelu(gate)*h written IN-PLACE over the gate buffer
// (each element read-then-written by exactly one thread; no cross-thread hazard).
__global__ void scan_C(const unsigned short* __restrict__ fg, const unsigned short* __restrict__ xbc,
                       const float* __restrict__ fb, const float* __restrict__ carry,
                       unsigned short* gateh) {
  int h = blockIdx.x * 256 + threadIdx.x;
  int ch = blockIdx.y;
  int n = blockIdx.z;
  const float c8 = 8.f * softplusf_(fb[h]);
  float s = carry[((size_t)n * NCH + ch) * H_M + h];
  size_t r = (size_t)n * T_S + (size_t)ch * LCH;
  for (int i = 0; i < LCH; i++, r++) {
    float forget = bf2f(fg[r * G2 + h]);
    float inp    = bf2f(fg[r * G2 + H_M + h]);
    float xb     = bf2f(xbc[r * H_M + h]);
    float alpha = __expf(-c8 * sigmoidf_(forget));
    float beta  = sqrtf(1.f - alpha * alpha + 1e-6f);
    float xs    = beta * sigmoidf_(inp) * xb;
    s = alpha * s + xs;
    float gate = bf2f(gateh[r * H_M + h]);
    gateh[r * H_M + h] = f2bf(geluf_(gate) * s);
  }
}

// ---------------- launcher ----------------
// Workspace layout (S = NT*H_M*2 = 50,331,648 B; peak = 4S + 9.4 MB ≈ 210.8 MB):
//   [0,S)    gate16 (GEMM1a out) -> scan_C in-place -> gh16 (GEMM3 A)
//   [S,2S)   xbpre16 (GEMM1b out, conv in; dead after conv)
//   [S,3S)   fg16 (GEMM2 out, overwrites xbpre16 + x16/Win16)
//   [2S,..)  x16 (33.6MB) + Win16 (6.3MB), live only during GEMM1
//   [3S,4S)  xbc16 (conv out; dead after scan_C, then reused for Wout16)
//   [4S,..)  Wg16 (9.4MB, dead after GEMM2) aliased by cA/cS/carry (4.7MB)
extern "C" void kernel_launch(void* const* d_in, const int* in_sizes, int n_in,
                              void* d_out, int out_size, void* d_ws, size_t ws_size,
                              hipStream_t stream) {
  const float* x    = (const float*)d_in[0];
  const float* Win  = (const float*)d_in[1];
  const float* cw   = (const float*)d_in[2];
  const float* cb   = (const float*)d_in[3];
  const float* Wg   = (const float*)d_in[4];
  const float* bg   = (const float*)d_in[5];
  const float* fb   = (const float*)d_in[6];
  const float* Wout = (const float*)d_in[7];
  float* out = (float*)d_out;
  (void)in_sizes; (void)n_in;

  const size_t S = (size_t)NT * H_M * 2;
  const size_t needed = 4 * S + (size_t)G2 * H_M * 2;
  if (ws_size < needed) {
    // Diagnostic fallback: don't fault, just zero the output (absmax will be ~0.457).
    zero_out<<<(out_size + 255) / 256, 256, 0, stream>>>(out, out_size);
    return;
  }

  char* base = (char*)d_ws;
  unsigned short* gate16  = (unsigned short*)(base);            // becomes gh16 in-place
  unsigned short* xbpre16 = (unsigned short*)(base + S);
  unsigned short* fg16    = (unsigned short*)(base + S);        // [S,3S) after conv
  unsigned short* x16     = (unsigned short*)(base + 2 * S);    // live during GEMM1 only
  unsigned short* Win16   = (unsigned short*)(base + 2 * S + (size_t)NT * D_M * 2);
  unsigned short* xbc16   = (unsigned short*)(base + 3 * S);
  unsigned short* Wg16    = (unsigned short*)(base + 4 * S);    // dead after GEMM2
  float* cA    = (float*)(base + 4 * S);                        // aliases Wg16 (after GEMM2)
  float* cS    = cA + (size_t)N_B * NCH * H_M;
  float* carry = cS + (size_t)N_B * NCH * H_M;
  unsigned short* Wout16  = (unsigned short*)(base + 3 * S);    // aliases xbc16 (after scan_C)

  // bf16 conversions needed before GEMM1/GEMM2
  cvt_bf16<<<(NT * D_M / 4 + 255) / 256, 256, 0, stream>>>(x, x16, NT * D_M / 4);
  cvt_bf16<<<(G2 * D_M / 4 + 255) / 256, 256, 0, stream>>>(Win, Win16, G2 * D_M / 4);
  cvt_bf16<<<(G2 * H_M / 4 + 255) / 256, 256, 0, stream>>>(Wg, Wg16, G2 * H_M / 4);

  // 1) gx = x @ W_in^T, split halves: gate -> gate16, xb -> xbpre16
  gemm_bt<false, true><<<dim3(H_M / BN, NT / BM), 256, 0, stream>>>(
      x16, Win16, gate16, nullptr, H_M, D_M);
  gemm_bt<false, true><<<dim3(H_M / BN, NT / BM), 256, 0, stream>>>(
      x16, Win16 + (size_t)H_M * D_M, xbpre16, nullptr, H_M, D_M);
  // 2) depthwise causal conv -> xbc16
  conv_dw<<<dim3(H_M / 256, T_S, N_B), 256, 0, stream>>>(xbpre16, cw, cb, xbc16);
  // 3) fg = xbc @ W_g^T + b_g  (overwrites xbpre16/x16/Win16 region)
  gemm_bt<true, true><<<dim3(G2 / BN, NT / BM), 256, 0, stream>>>(
      xbc16, Wg16, fg16, bg, G2, H_M);
  // 4) chunked linear scan + fused gelu(gate)*h (in-place over gate16)
  scan_A<<<dim3(H_M / 256, NCH, N_B), 256, 0, stream>>>(fg16, xbc16, fb, cA, cS);
  scan_B<<<dim3(H_M / 256, N_B), 256, 0, stream>>>(cA, cS, carry);
  scan_C<<<dim3(H_M / 256, NCH, N_B), 256, 0, stream>>>(fg16, xbc16, fb, carry, gate16);
  // 5) out = gh @ W_out^T  (fp32 out); Wout16 converted into dead xbc16 space
  cvt_bf16<<<(D_M * H_M / 4 + 255) / 256, 256, 0, stream>>>(Wout, Wout16, D_M * H_M / 4);
  gemm_bt<false, false><<<dim3(D_M / BN, NT / BM), 256, 0, stream>>>(
      gate16, Wout16, out, nullptr, D_M, H_M);
}

// Round 4
// 742.148 us; speedup vs baseline: 1.0512x; 1.0512x over previous
//
#include <hip/hip_runtime.h>
#include <stdint.h>
#include <math.h>

#define N_B 4
#define T_S 4096
#define D_M 1024
#define H_M 1536
#define NT  (N_B * T_S)   // 16384
#define G2  (2 * H_M)     // 3072
#define LCH 64            // timesteps per chunk
#define NCH 64            // chunks (LCH*NCH == T_S)

typedef __attribute__((ext_vector_type(8))) short short8;
typedef __attribute__((ext_vector_type(4))) float floatx4;

__device__ __forceinline__ unsigned short f2bf(float f) {
  unsigned u = __float_as_uint(f);
  u += 0x7fff + ((u >> 16) & 1);            // RNE
  return (unsigned short)(u >> 16);
}
__device__ __forceinline__ float bf2f(unsigned short u) {
  return __uint_as_float(((unsigned)u) << 16);
}
__device__ __forceinline__ float sigmoidf_(float x) { return 1.f / (1.f + __expf(-x)); }
__device__ __forceinline__ float softplusf_(float x) {
  return (x > 20.f) ? x : log1pf(__expf(x));
}
__device__ __forceinline__ float geluf_(float x) {
  return 0.5f * x * (1.f + erff(x * 0.70710678118654752f));
}

// ---------------- zero-fill fallback (diagnostic if ws_size too small) ----------------
__global__ void zero_out(float* __restrict__ out, int n) {
  int i = blockIdx.x * 256 + threadIdx.x;
  if (i < n) out[i] = 0.f;
}

// ---------------- fused f32 -> bf16 conversion of x, Win, Wg (one launch) ----------------
#define N4_X   (NT * D_M / 4)          // 4,194,304
#define N4_WIN (G2 * D_M / 4)          //   786,432
#define N4_WG  (G2 * H_M / 4)          // 1,179,648
__global__ void cvt3_bf16(const float* __restrict__ x, unsigned short* __restrict__ x16,
                          const float* __restrict__ win, unsigned short* __restrict__ win16,
                          const float* __restrict__ wg, unsigned short* __restrict__ wg16) {
  int i = blockIdx.x * 256 + threadIdx.x;
  const float* in; unsigned short* out;
  if (i < N4_X)                { in = x;   out = x16; }
  else if (i < N4_X + N4_WIN)  { in = win; out = win16; i -= N4_X; }
  else if (i < N4_X + N4_WIN + N4_WG) { in = wg; out = wg16; i -= N4_X + N4_WIN; }
  else return;
  float4 v = ((const float4*)in)[i];
  ushort4 o;
  o.x = f2bf(v.x); o.y = f2bf(v.y); o.z = f2bf(v.z); o.w = f2bf(v.w);
  ((ushort4*)out)[i] = o;
}

__global__ void cvt_bf16(const float* __restrict__ in, unsigned short* __restrict__ out, int n4) {
  int i = blockIdx.x * 256 + threadIdx.x;
  if (i >= n4) return;
  float4 v = ((const float4*)in)[i];
  ushort4 o;
  o.x = f2bf(v.x); o.y = f2bf(v.y); o.z = f2bf(v.z); o.w = f2bf(v.w);
  ((ushort4*)out)[i] = o;
}

// ---------------- bf16 MFMA GEMM: C[m,n] = sum_k A[m,k]*B[n,k] (+bias[n]) ----------------
// m97 structure: 128x128 tile, BK=32, 256 threads (4 waves, 2x2), 4x4 16x16x32 frags/wave,
// global_load_lds width 16. Output fp32 or bf16. SPLIT: cols [0,N/2) -> Cv, [N/2,N) -> Cv2,
// each stored with row stride N/2 (block is entirely in one half since N/2 % BN == 0).
#define BM 128
#define BN 128
#define BK 32

template<bool BIAS, bool OUT_BF16, bool SPLIT>
__global__ void gemm_bt(const unsigned short* __restrict__ A,
                        const unsigned short* __restrict__ B,
                        void* __restrict__ Cv, void* __restrict__ Cv2,
                        const float* __restrict__ bias,
                        int N, int K) {
  __shared__ unsigned short As[BM * BK];
  __shared__ unsigned short Bs[BN * BK];
  const int tid  = threadIdx.x;
  const int lane = tid & 63;
  const int wave = tid >> 6;
  const int bm = blockIdx.y * BM;
  const int bn = blockIdx.x * BN;
  const int wm = (wave >> 1) * 64;
  const int wn = (wave & 1) * 64;

  floatx4 acc[4][4];
#pragma unroll
  for (int i = 0; i < 4; i++)
#pragma unroll
    for (int j = 0; j < 4; j++)
      acc[i][j] = (floatx4){0.f, 0.f, 0.f, 0.f};

  const int c0 = tid, c1 = tid + 256;
  const unsigned short* Ag0 = A + (size_t)(bm + (c0 >> 2)) * K + (c0 & 3) * 8;
  const unsigned short* Ag1 = A + (size_t)(bm + (c1 >> 2)) * K + (c1 & 3) * 8;
  const unsigned short* Bg0 = B + (size_t)(bn + (c0 >> 2)) * K + (c0 & 3) * 8;
  const unsigned short* Bg1 = B + (size_t)(bn + (c1 >> 2)) * K + (c1 & 3) * 8;
  unsigned short* As0 = As + c0 * 8;
  unsigned short* As1 = As + c1 * 8;
  unsigned short* Bs0 = Bs + c0 * 8;
  unsigned short* Bs1 = Bs + c1 * 8;

  const int fr = lane & 15;
  const int kg = (lane >> 4) * 8;

  for (int k0 = 0; k0 < K; k0 += BK) {
    __builtin_amdgcn_global_load_lds((__attribute__((address_space(1))) void*)(Ag0 + k0),
                                     (__attribute__((address_space(3))) void*)As0, 16, 0, 0);
    __builtin_amdgcn_global_load_lds((__attribute__((address_space(1))) void*)(Ag1 + k0),
                                     (__attribute__((address_space(3))) void*)As1, 16, 0, 0);
    __builtin_amdgcn_global_load_lds((__attribute__((address_space(1))) void*)(Bg0 + k0),
                                     (__attribute__((address_space(3))) void*)Bs0, 16, 0, 0);
    __builtin_amdgcn_global_load_lds((__attribute__((address_space(1))) void*)(Bg1 + k0),
                                     (__attribute__((address_space(3))) void*)Bs1, 16, 0, 0);
    __syncthreads();

    short8 af[4], bf[4];
#pragma unroll
    for (int i = 0; i < 4; i++) {
      af[i] = *(const short8*)(As + (wm + i * 16 + fr) * BK + kg);
      bf[i] = *(const short8*)(Bs + (wn + i * 16 + fr) * BK + kg);
    }
#pragma unroll
    for (int i = 0; i < 4; i++)
#pragma unroll
      for (int j = 0; j < 4; j++)
        acc[i][j] = __builtin_amdgcn_mfma_f32_16x16x32_bf16(af[i], bf[j], acc[i][j], 0, 0, 0);
    __syncthreads();
  }

  // C/D layout (m89-verified): col = lane&15, row = (lane>>4)*4 + reg
  const int half  = SPLIT ? (N >> 1) : N;
  const bool hi   = SPLIT && (bn >= half);
  void* Cb        = hi ? Cv2 : Cv;
  const int coff  = hi ? half : 0;
  const int cn = lane & 15;
  const int rb = (lane >> 4) * 4;
#pragma unroll
  for (int j = 0; j < 4; j++) {
    const int col = bn + wn + j * 16 + cn;
    const float bv = BIAS ? bias[col] : 0.f;
#pragma unroll
    for (int i = 0; i < 4; i++) {
      const int row0 = bm + wm + i * 16 + rb;
#pragma unroll
      for (int r = 0; r < 4; r++) {
        float v = acc[i][j][r] + bv;
        size_t idx = (size_t)(row0 + r) * half + (col - coff);
        if (OUT_BF16) ((unsigned short*)Cb)[idx] = f2bf(v);
        else          ((float*)Cb)[idx] = v;
      }
    }
  }
}

// ---------------- depthwise causal conv (K=4) + bias ----------------
__global__ void conv_dw(const unsigned short* __restrict__ xbpre, const float* __restrict__ cw,
                        const float* __restrict__ cb, unsigned short* __restrict__ xbc16) {
  int h = blockIdx.x * 256 + threadIdx.x;
  int t = blockIdx.y;
  size_t nt = (size_t)blockIdx.z * T_S + t;
  const float w0 = cw[h * 4 + 0], w1 = cw[h * 4 + 1], w2 = cw[h * 4 + 2], w3 = cw[h * 4 + 3];
  size_t base = nt * H_M + h;
  float acc = cb[h] + w3 * bf2f(xbpre[base]);
  if (t >= 1) acc += w2 * bf2f(xbpre[base - H_M]);
  if (t >= 2) acc += w1 * bf2f(xbpre[base - 2 * (size_t)H_M]);
  if (t >= 3) acc += w0 * bf2f(xbpre[base - 3 * (size_t)H_M]);
  xbc16[base] = f2bf(acc);
}

// ---------------- chunked linear scan ----------------
// phase A: per (n, chunk, h): aprod = prod(alpha), s = local scan with zero init
__global__ void scan_A(const unsigned short* __restrict__ fg, const unsigned short* __restrict__ xbc,
                       const float* __restrict__ fb,
                       float* __restrict__ cA, float* __restrict__ cS) {
  int h = blockIdx.x * 256 + threadIdx.x;
  int ch = blockIdx.y;
  int n = blockIdx.z;
  const float c8 = 8.f * softplusf_(fb[h]);
  float ap = 1.f, s = 0.f;
  size_t r = (size_t)n * T_S + (size_t)ch * LCH;
  for (int i = 0; i < LCH; i++, r++) {
    float forget = bf2f(fg[r * G2 + h]);
    float inp    = bf2f(fg[r * G2 + H_M + h]);
    float xb     = bf2f(xbc[r * H_M + h]);
    float alpha = __expf(-c8 * sigmoidf_(forget));
    float beta  = sqrtf(1.f - alpha * alpha + 1e-6f);
    float xs    = beta * sigmoidf_(inp) * xb;
    s = alpha * s + xs;
    ap *= alpha;
  }
  size_t o = ((size_t)n * NCH + ch) * H_M + h;
  cA[o] = ap;
  cS[o] = s;
}

// phase C: per-block prescan of chunk summaries (L2-hot, <=63 iters) computes the
// carry-in, then replay with fused gelu(gate)*h written IN-PLACE over the gate buffer
// (each element read-then-written by exactly one thread; no cross-thread hazard).
__global__ void scan_C(const unsigned short* __restrict__ fg, const unsigned short* __restrict__ xbc,
                       const float* __restrict__ fb,
                       const float* __restrict__ cA, const float* __restrict__ cS,
                       unsigned short* gateh) {
  int h = blockIdx.x * 256 + threadIdx.x;
  int ch = blockIdx.y;
  int n = blockIdx.z;
  const float c8 = 8.f * softplusf_(fb[h]);
  float s = 0.f;
  for (int c = 0; c < ch; c++) {
    size_t o = ((size_t)n * NCH + c) * H_M + h;
    s = cA[o] * s + cS[o];
  }
  size_t r = (size_t)n * T_S + (size_t)ch * LCH;
  for (int i = 0; i < LCH; i++, r++) {
    float forget = bf2f(fg[r * G2 + h]);
    float inp    = bf2f(fg[r * G2 + H_M + h]);
    float xb     = bf2f(xbc[r * H_M + h]);
    float alpha = __expf(-c8 * sigmoidf_(forget));
    float beta  = sqrtf(1.f - alpha * alpha + 1e-6f);
    float xs    = beta * sigmoidf_(inp) * xb;
    s = alpha * s + xs;
    float gate = bf2f(gateh[r * H_M + h]);
    gateh[r * H_M + h] = f2bf(geluf_(gate) * s);
  }
}

// ---------------- launcher ----------------
// Workspace layout (S = NT*H_M*2 = 50,331,648 B; peak = 4S + 9.4 MB ≈ 210.8 MB):
//   [0,S)    gate16 (GEMM1 out, lo half) -> scan_C in-place -> gh16 (GEMM3 A)
//   [S,2S)   xbpre16 (GEMM1 out, hi half; conv in; dead after conv)
//   [S,3S)   fg16 (GEMM2 out, overwrites xbpre16 + x16/Win16)
//   [2S,..)  x16 (33.6MB) + Win16 (6.3MB), live only during GEMM1
//   [3S,4S)  xbc16 (conv out; dead after scan_C)
//   [4S,..)  Wg16 (9.4MB, dead after GEMM2) aliased by cA(1.5) + cS(1.5) + Wout16(3.1)
extern "C" void kernel_launch(void* const* d_in, const int* in_sizes, int n_in,
                              void* d_out, int out_size, void* d_ws, size_t ws_size,
                              hipStream_t stream) {
  const float* x    = (const float*)d_in[0];
  const float* Win  = (const float*)d_in[1];
  const float* cw   = (const float*)d_in[2];
  const float* cb   = (const float*)d_in[3];
  const float* Wg   = (const float*)d_in[4];
  const float* bg   = (const float*)d_in[5];
  const float* fb   = (const float*)d_in[6];
  const float* Wout = (const float*)d_in[7];
  float* out = (float*)d_out;
  (void)in_sizes; (void)n_in;

  const size_t S = (size_t)NT * H_M * 2;
  const size_t needed = 4 * S + (size_t)G2 * H_M * 2;
  if (ws_size < needed) {
    zero_out<<<(out_size + 255) / 256, 256, 0, stream>>>(out, out_size);
    return;
  }

  char* base = (char*)d_ws;
  unsigned short* gate16  = (unsigned short*)(base);            // becomes gh16 in-place
  unsigned short* xbpre16 = (unsigned short*)(base + S);
  unsigned short* fg16    = (unsigned short*)(base + S);        // [S,3S) after conv
  unsigned short* x16     = (unsigned short*)(base + 2 * S);    // live during GEMM1 only
  unsigned short* Win16   = (unsigned short*)(base + 2 * S + (size_t)NT * D_M * 2);
  unsigned short* xbc16   = (unsigned short*)(base + 3 * S);
  unsigned short* Wg16    = (unsigned short*)(base + 4 * S);    // dead after GEMM2
  float* cA    = (float*)(base + 4 * S);                        // aliases Wg16 (after GEMM2)
  float* cS    = cA + (size_t)N_B * NCH * H_M;
  unsigned short* Wout16  = (unsigned short*)(cS + (size_t)N_B * NCH * H_M);

  // fused bf16 conversions (x, Win, Wg)
  cvt3_bf16<<<(N4_X + N4_WIN + N4_WG + 255) / 256, 256, 0, stream>>>(
      x, x16, Win, Win16, Wg, Wg16);

  // 1) gx = x @ W_in^T, single dispatch, split output: gate16 | xbpre16
  gemm_bt<false, true, true><<<dim3(G2 / BN, NT / BM), 256, 0, stream>>>(
      x16, Win16, gate16, xbpre16, nullptr, G2, D_M);
  // 2) depthwise causal conv -> xbc16
  conv_dw<<<dim3(H_M / 256, T_S, N_B), 256, 0, stream>>>(xbpre16, cw, cb, xbc16);
  // 3) fg = xbc @ W_g^T + b_g  (overwrites xbpre16/x16/Win16 region)
  gemm_bt<true, true, false><<<dim3(G2 / BN, NT / BM), 256, 0, stream>>>(
      xbc16, Wg16, fg16, nullptr, bg, G2, H_M);
  // Wout cvt into the now-dead Wg16 slot (after cA/cS)
  cvt_bf16<<<(D_M * H_M / 4 + 255) / 256, 256, 0, stream>>>(Wout, Wout16, D_M * H_M / 4);
  // 4) chunked linear scan + fused gelu(gate)*h (in-place over gate16)
  scan_A<<<dim3(H_M / 256, NCH, N_B), 256, 0, stream>>>(fg16, xbc16, fb, cA, cS);
  scan_C<<<dim3(H_M / 256, NCH, N_B), 256, 0, stream>>>(fg16, xbc16, fb, cA, cS, gate16);
  // 5) out = gh @ W_out^T  (fp32 out)
  gemm_bt<false, false, false><<<dim3(D_M / BN, NT / BM), 256, 0, stream>>>(
      gate16, Wout16, out, nullptr, nullptr, D_M, H_M);
}

// Round 5
// 717.782 us; speedup vs baseline: 1.0869x; 1.0339x over previous
//
#include <hip/hip_runtime.h>
#include <stdint.h>
#include <math.h>

#define N_B 4
#define T_S 4096
#define D_M 1024
#define H_M 1536
#define NT  (N_B * T_S)   // 16384
#define G2  (2 * H_M)     // 3072
#define LCH 64            // timesteps per chunk
#define NCH 64            // chunks (LCH*NCH == T_S)

typedef __attribute__((ext_vector_type(8))) short short8;
typedef __attribute__((ext_vector_type(4))) float floatx4;

__device__ __forceinline__ unsigned short f2bf(float f) {
  unsigned u = __float_as_uint(f);
  u += 0x7fff + ((u >> 16) & 1);            // RNE
  return (unsigned short)(u >> 16);
}
__device__ __forceinline__ float bf2f(unsigned short u) {
  return __uint_as_float(((unsigned)u) << 16);
}
__device__ __forceinline__ float bf_lo(unsigned p) { return __uint_as_float(p << 16); }
__device__ __forceinline__ float bf_hi(unsigned p) { return __uint_as_float(p & 0xffff0000u); }
__device__ __forceinline__ unsigned bf_pack(float lo, float hi) {
  return ((unsigned)f2bf(lo)) | (((unsigned)f2bf(hi)) << 16);
}
__device__ __forceinline__ float sigmoidf_(float x) { return 1.f / (1.f + __expf(-x)); }
__device__ __forceinline__ float softplusf_(float x) {
  return (x > 20.f) ? x : log1pf(__expf(x));
}
__device__ __forceinline__ float geluf_(float x) {
  return 0.5f * x * (1.f + erff(x * 0.70710678118654752f));
}

// ---------------- zero-fill fallback (diagnostic if ws_size too small) ----------------
__global__ void zero_out(float* __restrict__ out, int n) {
  int i = blockIdx.x * 256 + threadIdx.x;
  if (i < n) out[i] = 0.f;
}

// ---------------- fused f32 -> bf16 conversion of x, Win, Wg (one launch) ----------------
#define N4_X   (NT * D_M / 4)          // 4,194,304
#define N4_WIN (G2 * D_M / 4)          //   786,432
#define N4_WG  (G2 * H_M / 4)          // 1,179,648
__global__ void cvt3_bf16(const float* __restrict__ x, unsigned short* __restrict__ x16,
                          const float* __restrict__ win, unsigned short* __restrict__ win16,
                          const float* __restrict__ wg, unsigned short* __restrict__ wg16) {
  int i = blockIdx.x * 256 + threadIdx.x;
  const float* in; unsigned short* out;
  if (i < N4_X)                { in = x;   out = x16; }
  else if (i < N4_X + N4_WIN)  { in = win; out = win16; i -= N4_X; }
  else if (i < N4_X + N4_WIN + N4_WG) { in = wg; out = wg16; i -= N4_X + N4_WIN; }
  else return;
  float4 v = ((const float4*)in)[i];
  ushort4 o;
  o.x = f2bf(v.x); o.y = f2bf(v.y); o.z = f2bf(v.z); o.w = f2bf(v.w);
  ((ushort4*)out)[i] = o;
}

__global__ void cvt_bf16(const float* __restrict__ in, unsigned short* __restrict__ out, int n4) {
  int i = blockIdx.x * 256 + threadIdx.x;
  if (i >= n4) return;
  float4 v = ((const float4*)in)[i];
  ushort4 o;
  o.x = f2bf(v.x); o.y = f2bf(v.y); o.z = f2bf(v.z); o.w = f2bf(v.w);
  ((ushort4*)out)[i] = o;
}

// ---------------- bf16 MFMA GEMM: C[m,n] = sum_k A[m,k]*B[n,k] (+bias[n]) ----------------
// m97 structure upgraded to BK=64: 128x128 tile, 256 threads (4 waves, 2x2),
// 4x4 16x16x32 frags/wave x 2 k-steps per barrier pair (32 MFMA / 2 barriers).
// LDS 2 x 16 KB. global_load_lds width 16 (4 chunks per thread per operand).
// SPLIT: cols [0,N/2) -> Cv, [N/2,N) -> Cv2, each with row stride N/2.
#define BM 128
#define BN 128
#define BK 64

template<bool BIAS, bool OUT_BF16, bool SPLIT>
__global__ void gemm_bt(const unsigned short* __restrict__ A,
                        const unsigned short* __restrict__ B,
                        void* __restrict__ Cv, void* __restrict__ Cv2,
                        const float* __restrict__ bias,
                        int N, int K) {
  __shared__ unsigned short As[BM * BK];   // 16 KB
  __shared__ unsigned short Bs[BN * BK];   // 16 KB
  const int tid  = threadIdx.x;
  const int lane = tid & 63;
  const int wave = tid >> 6;
  const int bm = blockIdx.y * BM;
  const int bn = blockIdx.x * BN;
  const int wm = (wave >> 1) * 64;
  const int wn = (wave & 1) * 64;

  floatx4 acc[4][4];
#pragma unroll
  for (int i = 0; i < 4; i++)
#pragma unroll
    for (int j = 0; j < 4; j++)
      acc[i][j] = (floatx4){0.f, 0.f, 0.f, 0.f};

  // staging: 1024 chunks of 16B per operand tile; thread covers chunks tid+256*q, q=0..3.
  // chunk c -> row c>>3, k-offset (c&7)*8.
  const unsigned short* Ag[4];
  const unsigned short* Bg[4];
  unsigned short* Asd[4];
  unsigned short* Bsd[4];
#pragma unroll
  for (int q = 0; q < 4; q++) {
    const int c = tid + 256 * q;
    Ag[q] = A + (size_t)(bm + (c >> 3)) * K + (c & 7) * 8;
    Bg[q] = B + (size_t)(bn + (c >> 3)) * K + (c & 7) * 8;
    Asd[q] = As + c * 8;
    Bsd[q] = Bs + c * 8;
  }

  const int fr = lane & 15;
  const int kg = (lane >> 4) * 8;

  for (int k0 = 0; k0 < K; k0 += BK) {
#pragma unroll
    for (int q = 0; q < 4; q++) {
      __builtin_amdgcn_global_load_lds((__attribute__((address_space(1))) void*)(Ag[q] + k0),
                                       (__attribute__((address_space(3))) void*)Asd[q], 16, 0, 0);
      __builtin_amdgcn_global_load_lds((__attribute__((address_space(1))) void*)(Bg[q] + k0),
                                       (__attribute__((address_space(3))) void*)Bsd[q], 16, 0, 0);
    }
    __syncthreads();

#pragma unroll
    for (int s = 0; s < 2; s++) {
      short8 af[4], bf[4];
#pragma unroll
      for (int i = 0; i < 4; i++) {
        af[i] = *(const short8*)(As + (wm + i * 16 + fr) * BK + s * 32 + kg);
        bf[i] = *(const short8*)(Bs + (wn + i * 16 + fr) * BK + s * 32 + kg);
      }
#pragma unroll
      for (int i = 0; i < 4; i++)
#pragma unroll
        for (int j = 0; j < 4; j++)
          acc[i][j] = __builtin_amdgcn_mfma_f32_16x16x32_bf16(af[i], bf[j], acc[i][j], 0, 0, 0);
    }
    __syncthreads();
  }

  // C/D layout (m89-verified): col = lane&15, row = (lane>>4)*4 + reg
  const int half  = SPLIT ? (N >> 1) : N;
  const bool hi   = SPLIT && (bn >= half);
  void* Cb        = hi ? Cv2 : Cv;
  const int coff  = hi ? half : 0;
  const int cn = lane & 15;
  const int rb = (lane >> 4) * 4;
#pragma unroll
  for (int j = 0; j < 4; j++) {
    const int col = bn + wn + j * 16 + cn;
    const float bv = BIAS ? bias[col] : 0.f;
#pragma unroll
    for (int i = 0; i < 4; i++) {
      const int row0 = bm + wm + i * 16 + rb;
#pragma unroll
      for (int r = 0; r < 4; r++) {
        float v = acc[i][j][r] + bv;
        size_t idx = (size_t)(row0 + r) * half + (col - coff);
        if (OUT_BF16) ((unsigned short*)Cb)[idx] = f2bf(v);
        else          ((float*)Cb)[idx] = v;
      }
    }
  }
}

// ---------------- depthwise causal conv (K=4) + bias, 2 channels/thread ----------------
__global__ void conv_dw(const unsigned int* __restrict__ xbpre2, const float* __restrict__ cw,
                        const float* __restrict__ cb, unsigned int* __restrict__ xbc2) {
  int i0 = blockIdx.x * 256 + threadIdx.x;       // pair index, 0..H_M/2-1
  int t = blockIdx.y;
  size_t nt = (size_t)blockIdx.z * T_S + t;
  const int h = 2 * i0;
  const float4 wa = ((const float4*)cw)[h];      // taps for channel h
  const float4 wb = ((const float4*)cw)[h + 1];  // taps for channel h+1
  const float2 cb2 = ((const float2*)cb)[i0];
  size_t base = nt * (H_M / 2) + i0;
  unsigned p0 = xbpre2[base];
  float aa = cb2.x + wa.w * bf_lo(p0);
  float ab = cb2.y + wb.w * bf_hi(p0);
  if (t >= 1) { unsigned p = xbpre2[base - H_M / 2];
    aa += wa.z * bf_lo(p); ab += wb.z * bf_hi(p); }
  if (t >= 2) { unsigned p = xbpre2[base - 2 * (size_t)(H_M / 2)];
    aa += wa.y * bf_lo(p); ab += wb.y * bf_hi(p); }
  if (t >= 3) { unsigned p = xbpre2[base - 3 * (size_t)(H_M / 2)];
    aa += wa.x * bf_lo(p); ab += wb.x * bf_hi(p); }
  xbc2[base] = bf_pack(aa, ab);
}

// ---------------- chunked linear scan (2 channels/thread) ----------------
// phase A: per (n, chunk, pair): aprod = prod(alpha), s = local scan with zero init
__global__ void scan_A(const unsigned int* __restrict__ fg2, const unsigned int* __restrict__ xbc2,
                       const float* __restrict__ fb,
                       float2* __restrict__ cA2, float2* __restrict__ cS2) {
  int i0 = blockIdx.x * 256 + threadIdx.x;       // pair index
  int ch = blockIdx.y;
  int n = blockIdx.z;
  const float2 fb2 = ((const float2*)fb)[i0];
  const float c8a = 8.f * softplusf_(fb2.x);
  const float c8b = 8.f * softplusf_(fb2.y);
  float apa = 1.f, sa = 0.f, apb = 1.f, sb = 0.f;
  size_t r = (size_t)n * T_S + (size_t)ch * LCH;
  for (int i = 0; i < LCH; i++, r++) {
    unsigned pf = fg2[r * (G2 / 2) + i0];
    unsigned pi = fg2[r * (G2 / 2) + H_M / 2 + i0];
    unsigned px = xbc2[r * (H_M / 2) + i0];
    float alpha_a = __expf(-c8a * sigmoidf_(bf_lo(pf)));
    float alpha_b = __expf(-c8b * sigmoidf_(bf_hi(pf)));
    float beta_a = sqrtf(1.f - alpha_a * alpha_a + 1e-6f);
    float beta_b = sqrtf(1.f - alpha_b * alpha_b + 1e-6f);
    sa = alpha_a * sa + beta_a * sigmoidf_(bf_lo(pi)) * bf_lo(px);
    sb = alpha_b * sb + beta_b * sigmoidf_(bf_hi(pi)) * bf_hi(px);
    apa *= alpha_a;
    apb *= alpha_b;
  }
  size_t o = ((size_t)n * NCH + ch) * (H_M / 2) + i0;
  cA2[o] = make_float2(apa, apb);
  cS2[o] = make_float2(sa, sb);
}

// phase C: per-block prescan of chunk summaries (L2-hot) computes the carry-in,
// then replay with fused gelu(gate)*h written IN-PLACE over the gate buffer.
__global__ void scan_C(const unsigned int* __restrict__ fg2, const unsigned int* __restrict__ xbc2,
                       const float* __restrict__ fb,
                       const float2* __restrict__ cA2, const float2* __restrict__ cS2,
                       unsigned int* gateh2) {
  int i0 = blockIdx.x * 256 + threadIdx.x;
  int ch = blockIdx.y;
  int n = blockIdx.z;
  const float2 fb2 = ((const float2*)fb)[i0];
  const float c8a = 8.f * softplusf_(fb2.x);
  const float c8b = 8.f * softplusf_(fb2.y);
  float sa = 0.f, sb = 0.f;
  for (int c = 0; c < ch; c++) {
    size_t o = ((size_t)n * NCH + c) * (H_M / 2) + i0;
    float2 a = cA2[o], s = cS2[o];
    sa = a.x * sa + s.x;
    sb = a.y * sb + s.y;
  }
  size_t r = (size_t)n * T_S + (size_t)ch * LCH;
  for (int i = 0; i < LCH; i++, r++) {
    unsigned pf = fg2[r * (G2 / 2) + i0];
    unsigned pi = fg2[r * (G2 / 2) + H_M / 2 + i0];
    unsigned px = xbc2[r * (H_M / 2) + i0];
    float alpha_a = __expf(-c8a * sigmoidf_(bf_lo(pf)));
    float alpha_b = __expf(-c8b * sigmoidf_(bf_hi(pf)));
    float beta_a = sqrtf(1.f - alpha_a * alpha_a + 1e-6f);
    float beta_b = sqrtf(1.f - alpha_b * alpha_b + 1e-6f);
    sa = alpha_a * sa + beta_a * sigmoidf_(bf_lo(pi)) * bf_lo(px);
    sb = alpha_b * sb + beta_b * sigmoidf_(bf_hi(pi)) * bf_hi(px);
    unsigned pg = gateh2[r * (H_M / 2) + i0];
    gateh2[r * (H_M / 2) + i0] = bf_pack(geluf_(bf_lo(pg)) * sa, geluf_(bf_hi(pg)) * sb);
  }
}

// ---------------- launcher ----------------
// Workspace layout (S = NT*H_M*2 = 50,331,648 B; peak = 4S + 9.4 MB ≈ 210.8 MB):
//   [0,S)    gate16 (GEMM1 out, lo half) -> scan_C in-place -> gh16 (GEMM3 A)
//   [S,2S)   xbpre16 (GEMM1 out, hi half; conv in; dead after conv)
//   [S,3S)   fg16 (GEMM2 out, overwrites xbpre16 + x16/Win16)
//   [2S,..)  x16 (33.6MB) + Win16 (6.3MB), live only during GEMM1
//   [3S,4S)  xbc16 (conv out; dead after scan_C)
//   [4S,..)  Wg16 (9.4MB, dead after GEMM2) aliased by cA(1.5) + cS(1.5) + Wout16(3.1)
extern "C" void kernel_launch(void* const* d_in, const int* in_sizes, int n_in,
                              void* d_out, int out_size, void* d_ws, size_t ws_size,
                              hipStream_t stream) {
  const float* x    = (const float*)d_in[0];
  const float* Win  = (const float*)d_in[1];
  const float* cw   = (const float*)d_in[2];
  const float* cb   = (const float*)d_in[3];
  const float* Wg   = (const float*)d_in[4];
  const float* bg   = (const float*)d_in[5];
  const float* fb   = (const float*)d_in[6];
  const float* Wout = (const float*)d_in[7];
  float* out = (float*)d_out;
  (void)in_sizes; (void)n_in;

  const size_t S = (size_t)NT * H_M * 2;
  const size_t needed = 4 * S + (size_t)G2 * H_M * 2;
  if (ws_size < needed) {
    zero_out<<<(out_size + 255) / 256, 256, 0, stream>>>(out, out_size);
    return;
  }

  char* base = (char*)d_ws;
  unsigned short* gate16  = (unsigned short*)(base);            // becomes gh16 in-place
  unsigned short* xbpre16 = (unsigned short*)(base + S);
  unsigned short* fg16    = (unsigned short*)(base + S);        // [S,3S) after conv
  unsigned short* x16     = (unsigned short*)(base + 2 * S);    // live during GEMM1 only
  unsigned short* Win16   = (unsigned short*)(base + 2 * S + (size_t)NT * D_M * 2);
  unsigned short* xbc16   = (unsigned short*)(base + 3 * S);
  unsigned short* Wg16    = (unsigned short*)(base + 4 * S);    // dead after GEMM2
  float* cA    = (float*)(base + 4 * S);                        // aliases Wg16 (after GEMM2)
  float* cS    = cA + (size_t)N_B * NCH * H_M;
  unsigned short* Wout16  = (unsigned short*)(cS + (size_t)N_B * NCH * H_M);

  // fused bf16 conversions (x, Win, Wg)
  cvt3_bf16<<<(N4_X + N4_WIN + N4_WG + 255) / 256, 256, 0, stream>>>(
      x, x16, Win, Win16, Wg, Wg16);

  // 1) gx = x @ W_in^T, single dispatch, split output: gate16 | xbpre16
  gemm_bt<false, true, true><<<dim3(G2 / BN, NT / BM), 256, 0, stream>>>(
      x16, Win16, gate16, xbpre16, nullptr, G2, D_M);
  // 2) depthwise causal conv -> xbc16 (2 ch/thread)
  conv_dw<<<dim3(H_M / 512, T_S, N_B), 256, 0, stream>>>(
      (const unsigned int*)xbpre16, cw, cb, (unsigned int*)xbc16);
  // 3) fg = xbc @ W_g^T + b_g  (overwrites xbpre16/x16/Win16 region)
  gemm_bt<true, true, false><<<dim3(G2 / BN, NT / BM), 256, 0, stream>>>(
      xbc16, Wg16, fg16, nullptr, bg, G2, H_M);
  // Wout cvt into the now-dead Wg16 slot (after cA/cS)
  cvt_bf16<<<(D_M * H_M / 4 + 255) / 256, 256, 0, stream>>>(Wout, Wout16, D_M * H_M / 4);
  // 4) chunked linear scan + fused gelu(gate)*h (in-place over gate16), 2 ch/thread
  scan_A<<<dim3(H_M / 512, NCH, N_B), 256, 0, stream>>>(
      (const unsigned int*)fg16, (const unsigned int*)xbc16, fb, (float2*)cA, (float2*)cS);
  scan_C<<<dim3(H_M / 512, NCH, N_B), 256, 0, stream>>>(
      (const unsigned int*)fg16, (const unsigned int*)xbc16, fb,
      (const float2*)cA, (const float2*)cS, (unsigned int*)gate16);
  // 5) out = gh @ W_out^T  (fp32 out)
  gemm_bt<false, false, false><<<dim3(D_M / BN, NT / BM), 256, 0, stream>>>(
      gate16, Wout16, out, nullptr, nullptr, D_M, H_M);
}

// Round 6
// 699.113 us; speedup vs baseline: 1.1159x; 1.0267x over previous
//
#include <hip/hip_runtime.h>
#include <stdint.h>
#include <math.h>

#define N_B 4
#define T_S 4096
#define D_M 1024
#define H_M 1536
#define NT  (N_B * T_S)   // 16384
#define G2  (2 * H_M)     // 3072
#define LCH 64            // timesteps per chunk
#define NCH 64            // chunks (LCH*NCH == T_S)

typedef __attribute__((ext_vector_type(8))) short short8;
typedef __attribute__((ext_vector_type(4))) float floatx4;

__device__ __forceinline__ unsigned short f2bf(float f) {
  unsigned u = __float_as_uint(f);
  u += 0x7fff + ((u >> 16) & 1);            // RNE
  return (unsigned short)(u >> 16);
}
__device__ __forceinline__ float bf2f(unsigned short u) {
  return __uint_as_float(((unsigned)u) << 16);
}
__device__ __forceinline__ float bf_lo(unsigned p) { return __uint_as_float(p << 16); }
__device__ __forceinline__ float bf_hi(unsigned p) { return __uint_as_float(p & 0xffff0000u); }
__device__ __forceinline__ unsigned bf_pack(float lo, float hi) {
  return ((unsigned)f2bf(lo)) | (((unsigned)f2bf(hi)) << 16);
}
__device__ __forceinline__ float sigmoidf_(float x) { return 1.f / (1.f + __expf(-x)); }
__device__ __forceinline__ float softplusf_(float x) {
  return (x > 20.f) ? x : log1pf(__expf(x));
}
__device__ __forceinline__ float geluf_(float x) {
  return 0.5f * x * (1.f + erff(x * 0.70710678118654752f));
}

// ---------------- zero-fill fallback (diagnostic if ws_size too small) ----------------
__global__ void zero_out(float* __restrict__ out, int n) {
  int i = blockIdx.x * 256 + threadIdx.x;
  if (i < n) out[i] = 0.f;
}

// ---------------- fused f32 -> bf16 conversion of x, Win, Wg (one launch) ----------------
#define N4_X   (NT * D_M / 4)          // 4,194,304
#define N4_WIN (G2 * D_M / 4)          //   786,432
#define N4_WG  (G2 * H_M / 4)          // 1,179,648
__global__ void cvt3_bf16(const float* __restrict__ x, unsigned short* __restrict__ x16,
                          const float* __restrict__ win, unsigned short* __restrict__ win16,
                          const float* __restrict__ wg, unsigned short* __restrict__ wg16) {
  int i = blockIdx.x * 256 + threadIdx.x;
  const float* in; unsigned short* out;
  if (i < N4_X)                { in = x;   out = x16; }
  else if (i < N4_X + N4_WIN)  { in = win; out = win16; i -= N4_X; }
  else if (i < N4_X + N4_WIN + N4_WG) { in = wg; out = wg16; i -= N4_X + N4_WIN; }
  else return;
  float4 v = ((const float4*)in)[i];
  ushort4 o;
  o.x = f2bf(v.x); o.y = f2bf(v.y); o.z = f2bf(v.z); o.w = f2bf(v.w);
  ((ushort4*)out)[i] = o;
}

__global__ void cvt_bf16(const float* __restrict__ in, unsigned short* __restrict__ out, int n4) {
  int i = blockIdx.x * 256 + threadIdx.x;
  if (i >= n4) return;
  float4 v = ((const float4*)in)[i];
  ushort4 o;
  o.x = f2bf(v.x); o.y = f2bf(v.y); o.z = f2bf(v.z); o.w = f2bf(v.w);
  ((ushort4*)out)[i] = o;
}

// ---------------- bf16 MFMA GEMM: C[m,n] = sum_k A[m,k]*B[n,k] (+bias[n]) ----------------
// BK=64, 128x128 tile, 256 threads (4 waves, 2x2), 32 MFMA / barrier pair.
// XOR-swizzled LDS k-slots: staging chunk (row r, slot s) holds global k-chunk s^(r&7);
// exploits global_load_lds per-lane GLOBAL addressing (LDS dest must stay contiguous).
// Spreads quad ds_read_b128 across all 32 banks (structural-minimum drain).
// SPLIT: cols [0,N/2) -> Cv, [N/2,N) -> Cv2, each with row stride N/2.
#define BM 128
#define BN 128
#define BK 64

template<bool BIAS, bool OUT_BF16, bool SPLIT>
__global__ void gemm_bt(const unsigned short* __restrict__ A,
                        const unsigned short* __restrict__ B,
                        void* __restrict__ Cv, void* __restrict__ Cv2,
                        const float* __restrict__ bias,
                        int N, int K) {
  __shared__ unsigned short As[BM * BK];   // 16 KB
  __shared__ unsigned short Bs[BN * BK];   // 16 KB
  const int tid  = threadIdx.x;
  const int lane = tid & 63;
  const int wave = tid >> 6;
  const int bm = blockIdx.y * BM;
  const int bn = blockIdx.x * BN;
  const int wm = (wave >> 1) * 64;
  const int wn = (wave & 1) * 64;

  floatx4 acc[4][4];
#pragma unroll
  for (int i = 0; i < 4; i++)
#pragma unroll
    for (int j = 0; j < 4; j++)
      acc[i][j] = (floatx4){0.f, 0.f, 0.f, 0.f};

  // staging: 1024 chunks of 16B per operand tile; thread covers chunks tid+256*q.
  // chunk c -> LDS row r=c>>3 slot c&7; fetches GLOBAL k-chunk (c&7)^(r&7).
  const unsigned short* Ag[4];
  const unsigned short* Bg[4];
  unsigned short* Asd[4];
  unsigned short* Bsd[4];
#pragma unroll
  for (int q = 0; q < 4; q++) {
    const int c = tid + 256 * q;
    const int r = c >> 3;
    const int g = (c & 7) ^ (r & 7);           // swizzled global k-chunk
    Ag[q] = A + (size_t)(bm + r) * K + g * 8;
    Bg[q] = B + (size_t)(bn + r) * K + g * 8;
    Asd[q] = As + c * 8;
    Bsd[q] = Bs + c * 8;
  }

  const int fr = lane & 15;
  const int kq = lane >> 4;                    // k-quad (0..3) within 32-elem half

  for (int k0 = 0; k0 < K; k0 += BK) {
#pragma unroll
    for (int q = 0; q < 4; q++) {
      __builtin_amdgcn_global_load_lds((__attribute__((address_space(1))) void*)(Ag[q] + k0),
                                       (__attribute__((address_space(3))) void*)Asd[q], 16, 0, 0);
      __builtin_amdgcn_global_load_lds((__attribute__((address_space(1))) void*)(Bg[q] + k0),
                                       (__attribute__((address_space(3))) void*)Bsd[q], 16, 0, 0);
    }
    __syncthreads();

#pragma unroll
    for (int s = 0; s < 2; s++) {
      short8 af[4], bf[4];
#pragma unroll
      for (int i = 0; i < 4; i++) {
        const int slotA = ((s * 4 + kq) ^ (fr & 7)) * 8;   // swizzled LDS slot
        af[i] = *(const short8*)(As + (wm + i * 16 + fr) * BK + slotA);
        bf[i] = *(const short8*)(Bs + (wn + i * 16 + fr) * BK + slotA);
      }
#pragma unroll
      for (int i = 0; i < 4; i++)
#pragma unroll
        for (int j = 0; j < 4; j++)
          acc[i][j] = __builtin_amdgcn_mfma_f32_16x16x32_bf16(af[i], bf[j], acc[i][j], 0, 0, 0);
    }
    __syncthreads();
  }

  // C/D layout (m89-verified): col = lane&15, row = (lane>>4)*4 + reg
  const int half  = SPLIT ? (N >> 1) : N;
  const bool hi   = SPLIT && (bn >= half);
  void* Cb        = hi ? Cv2 : Cv;
  const int coff  = hi ? half : 0;
  const int cn = lane & 15;
  const int rb = (lane >> 4) * 4;
#pragma unroll
  for (int j = 0; j < 4; j++) {
    const int col = bn + wn + j * 16 + cn;
    const float bv = BIAS ? bias[col] : 0.f;
#pragma unroll
    for (int i = 0; i < 4; i++) {
      const int row0 = bm + wm + i * 16 + rb;
#pragma unroll
      for (int r = 0; r < 4; r++) {
        float v = acc[i][j][r] + bv;
        size_t idx = (size_t)(row0 + r) * half + (col - coff);
        if (OUT_BF16) ((unsigned short*)Cb)[idx] = f2bf(v);
        else          ((float*)Cb)[idx] = v;
      }
    }
  }
}

// ---------------- depthwise causal conv (K=4) + bias, 2 channels/thread ----------------
__global__ void conv_dw(const unsigned int* __restrict__ xbpre2, const float* __restrict__ cw,
                        const float* __restrict__ cb, unsigned int* __restrict__ xbc2) {
  int i0 = blockIdx.x * 256 + threadIdx.x;       // pair index, 0..H_M/2-1
  int t = blockIdx.y;
  size_t nt = (size_t)blockIdx.z * T_S + t;
  const int h = 2 * i0;
  const float4 wa = ((const float4*)cw)[h];      // taps for channel h
  const float4 wb = ((const float4*)cw)[h + 1];  // taps for channel h+1
  const float2 cb2 = ((const float2*)cb)[i0];
  size_t base = nt * (H_M / 2) + i0;
  unsigned p0 = xbpre2[base];
  float aa = cb2.x + wa.w * bf_lo(p0);
  float ab = cb2.y + wb.w * bf_hi(p0);
  if (t >= 1) { unsigned p = xbpre2[base - H_M / 2];
    aa += wa.z * bf_lo(p); ab += wb.z * bf_hi(p); }
  if (t >= 2) { unsigned p = xbpre2[base - 2 * (size_t)(H_M / 2)];
    aa += wa.y * bf_lo(p); ab += wb.y * bf_hi(p); }
  if (t >= 3) { unsigned p = xbpre2[base - 3 * (size_t)(H_M / 2)];
    aa += wa.x * bf_lo(p); ab += wb.x * bf_hi(p); }
  xbc2[base] = bf_pack(aa, ab);
}

// ---------------- chunked linear scan (2 channels/thread) ----------------
__global__ void scan_A(const unsigned int* __restrict__ fg2, const unsigned int* __restrict__ xbc2,
                       const float* __restrict__ fb,
                       float2* __restrict__ cA2, float2* __restrict__ cS2) {
  int i0 = blockIdx.x * 256 + threadIdx.x;       // pair index
  int ch = blockIdx.y;
  int n = blockIdx.z;
  const float2 fb2 = ((const float2*)fb)[i0];
  const float c8a = 8.f * softplusf_(fb2.x);
  const float c8b = 8.f * softplusf_(fb2.y);
  float apa = 1.f, sa = 0.f, apb = 1.f, sb = 0.f;
  size_t r = (size_t)n * T_S + (size_t)ch * LCH;
  for (int i = 0; i < LCH; i++, r++) {
    unsigned pf = fg2[r * (G2 / 2) + i0];
    unsigned pi = fg2[r * (G2 / 2) + H_M / 2 + i0];
    unsigned px = xbc2[r * (H_M / 2) + i0];
    float alpha_a = __expf(-c8a * sigmoidf_(bf_lo(pf)));
    float alpha_b = __expf(-c8b * sigmoidf_(bf_hi(pf)));
    float beta_a = sqrtf(1.f - alpha_a * alpha_a + 1e-6f);
    float beta_b = sqrtf(1.f - alpha_b * alpha_b + 1e-6f);
    sa = alpha_a * sa + beta_a * sigmoidf_(bf_lo(pi)) * bf_lo(px);
    sb = alpha_b * sb + beta_b * sigmoidf_(bf_hi(pi)) * bf_hi(px);
    apa *= alpha_a;
    apb *= alpha_b;
  }
  size_t o = ((size_t)n * NCH + ch) * (H_M / 2) + i0;
  cA2[o] = make_float2(apa, apb);
  cS2[o] = make_float2(sa, sb);
}

// phase C: per-block prescan of chunk summaries (L2-hot) computes the carry-in,
// then replay with fused gelu(gate)*h written IN-PLACE over the gate buffer.
__global__ void scan_C(const unsigned int* __restrict__ fg2, const unsigned int* __restrict__ xbc2,
                       const float* __restrict__ fb,
                       const float2* __restrict__ cA2, const float2* __restrict__ cS2,
                       unsigned int* gateh2) {
  int i0 = blockIdx.x * 256 + threadIdx.x;
  int ch = blockIdx.y;
  int n = blockIdx.z;
  const float2 fb2 = ((const float2*)fb)[i0];
  const float c8a = 8.f * softplusf_(fb2.x);
  const float c8b = 8.f * softplusf_(fb2.y);
  float sa = 0.f, sb = 0.f;
  for (int c = 0; c < ch; c++) {
    size_t o = ((size_t)n * NCH + c) * (H_M / 2) + i0;
    float2 a = cA2[o], s = cS2[o];
    sa = a.x * sa + s.x;
    sb = a.y * sb + s.y;
  }
  size_t r = (size_t)n * T_S + (size_t)ch * LCH;
  for (int i = 0; i < LCH; i++, r++) {
    unsigned pf = fg2[r * (G2 / 2) + i0];
    unsigned pi = fg2[r * (G2 / 2) + H_M / 2 + i0];
    unsigned px = xbc2[r * (H_M / 2) + i0];
    float alpha_a = __expf(-c8a * sigmoidf_(bf_lo(pf)));
    float alpha_b = __expf(-c8b * sigmoidf_(bf_hi(pf)));
    float beta_a = sqrtf(1.f - alpha_a * alpha_a + 1e-6f);
    float beta_b = sqrtf(1.f - alpha_b * alpha_b + 1e-6f);
    sa = alpha_a * sa + beta_a * sigmoidf_(bf_lo(pi)) * bf_lo(px);
    sb = alpha_b * sb + beta_b * sigmoidf_(bf_hi(pi)) * bf_hi(px);
    unsigned pg = gateh2[r * (H_M / 2) + i0];
    gateh2[r * (H_M / 2) + i0] = bf_pack(geluf_(bf_lo(pg)) * sa, geluf_(bf_hi(pg)) * sb);
  }
}

// ---------------- launcher ----------------
// Workspace layout (S = NT*H_M*2 = 50,331,648 B; peak = 4S + 9.4 MB ≈ 210.8 MB):
//   [0,S)    gate16 (GEMM1 out, lo half) -> scan_C in-place -> gh16 (GEMM3 A)
//   [S,2S)   xbpre16 (GEMM1 out, hi half; conv in; dead after conv)
//   [S,3S)   fg16 (GEMM2 out, overwrites xbpre16 + x16/Win16)
//   [2S,..)  x16 (33.6MB) + Win16 (6.3MB), live only during GEMM1
//   [3S,4S)  xbc16 (conv out; dead after scan_C)
//   [4S,..)  Wg16 (9.4MB, dead after GEMM2) aliased by cA(1.5) + cS(1.5) + Wout16(3.1)
extern "C" void kernel_launch(void* const* d_in, const int* in_sizes, int n_in,
                              void* d_out, int out_size, void* d_ws, size_t ws_size,
                              hipStream_t stream) {
  const float* x    = (const float*)d_in[0];
  const float* Win  = (const float*)d_in[1];
  const float* cw   = (const float*)d_in[2];
  const float* cb   = (const float*)d_in[3];
  const float* Wg   = (const float*)d_in[4];
  const float* bg   = (const float*)d_in[5];
  const float* fb   = (const float*)d_in[6];
  const float* Wout = (const float*)d_in[7];
  float* out = (float*)d_out;
  (void)in_sizes; (void)n_in;

  const size_t S = (size_t)NT * H_M * 2;
  const size_t needed = 4 * S + (size_t)G2 * H_M * 2;
  if (ws_size < needed) {
    zero_out<<<(out_size + 255) / 256, 256, 0, stream>>>(out, out_size);
    return;
  }

  char* base = (char*)d_ws;
  unsigned short* gate16  = (unsigned short*)(base);            // becomes gh16 in-place
  unsigned short* xbpre16 = (unsigned short*)(base + S);
  unsigned short* fg16    = (unsigned short*)(base + S);        // [S,3S) after conv
  unsigned short* x16     = (unsigned short*)(base + 2 * S);    // live during GEMM1 only
  unsigned short* Win16   = (unsigned short*)(base + 2 * S + (size_t)NT * D_M * 2);
  unsigned short* xbc16   = (unsigned short*)(base + 3 * S);
  unsigned short* Wg16    = (unsigned short*)(base + 4 * S);    // dead after GEMM2
  float* cA    = (float*)(base + 4 * S);                        // aliases Wg16 (after GEMM2)
  float* cS    = cA + (size_t)N_B * NCH * H_M;
  unsigned short* Wout16  = (unsigned short*)(cS + (size_t)N_B * NCH * H_M);

  // fused bf16 conversions (x, Win, Wg)
  cvt3_bf16<<<(N4_X + N4_WIN + N4_WG + 255) / 256, 256, 0, stream>>>(
      x, x16, Win, Win16, Wg, Wg16);

  // 1) gx = x @ W_in^T, single dispatch, split output: gate16 | xbpre16
  gemm_bt<false, true, true><<<dim3(G2 / BN, NT / BM), 256, 0, stream>>>(
      x16, Win16, gate16, xbpre16, nullptr, G2, D_M);
  // 2) depthwise causal conv -> xbc16 (2 ch/thread)
  conv_dw<<<dim3(H_M / 512, T_S, N_B), 256, 0, stream>>>(
      (const unsigned int*)xbpre16, cw, cb, (unsigned int*)xbc16);
  // 3) fg = xbc @ W_g^T + b_g  (overwrites xbpre16/x16/Win16 region)
  gemm_bt<true, true, false><<<dim3(G2 / BN, NT / BM), 256, 0, stream>>>(
      xbc16, Wg16, fg16, nullptr, bg, G2, H_M);
  // Wout cvt into the now-dead Wg16 slot (after cA/cS)
  cvt_bf16<<<(D_M * H_M / 4 + 255) / 256, 256, 0, stream>>>(Wout, Wout16, D_M * H_M / 4);
  // 4) chunked linear scan + fused gelu(gate)*h (in-place over gate16), 2 ch/thread
  scan_A<<<dim3(H_M / 512, NCH, N_B), 256, 0, stream>>>(
      (const unsigned int*)fg16, (const unsigned int*)xbc16, fb, (float2*)cA, (float2*)cS);
  scan_C<<<dim3(H_M / 512, NCH, N_B), 256, 0, stream>>>(
      (const unsigned int*)fg16, (const unsigned int*)xbc16, fb,
      (const float2*)cA, (const float2*)cS, (unsigned int*)gate16);
  // 5) out = gh @ W_out^T  (fp32 out)
  gemm_bt<false, false, false><<<dim3(D_M / BN, NT / BM), 256, 0, stream>>>(
      gate16, Wout16, out, nullptr, nullptr, D_M, H_M);
}